// Round 1
// baseline (4865.575 us; speedup 1.0000x reference)
//
#include <hip/hip_runtime.h>
#include <math.h>

// SA_Layer2 — ROUND 6: MFMA bf16 projections.
// k1/k3/k5 (the three 1x1-conv GEMMs) replaced by one templated MFMA GEMM:
//   per batch b: Out[M x 8192] = W[M x 512] * X[512 x 8192] (+bias)
//   MODE 0: W=qk_w  M=128, no bias, out -> Qs   bf16 [s][h][128]
//   MODE 1: W=v_w   M=512, v_b,     out -> Vt   bf16 [s][i][512]
//   MODE 2: W=t_w   M=512, t_b, X = (x - XR),   out -> T fp32 x-layout
// Structure: 128x128 tile, BK=64, 256 thr (4 waves), wave = 64x64 = 4x4 frags
// of v_mfma_f32_16x16x32_bf16, fp32 acc. Reg-staged global->LDS with fp32->bf16
// convert; LDS tiles [row][K] K-contiguous with T2 XOR swizzle (granule^row&7)
// so frag ds_read_b128 is <=2-way (free, m136). X-tile transposed at staging
// (global reads stay coalesced: lanes read consecutive n per k-row).
// (x - XR) fused into MODE 2 staging -> ws layout UNCHANGED from round 5.
// k2/k4 unchanged this round; k6/k7 float4-vectorized.

typedef unsigned short u16;
typedef __attribute__((ext_vector_type(4))) float f32x4;
typedef __attribute__((ext_vector_type(8))) short s16x8;
typedef __attribute__((ext_vector_type(4))) u16  u16x4;

__device__ __forceinline__ float b2f(u16 u) {
    unsigned x = ((unsigned)u) << 16;
    float f;
    __builtin_memcpy(&f, &x, 4);
    return f;
}
__device__ __forceinline__ u16 f2b(float f) {
    unsigned x;
    __builtin_memcpy(&x, &f, 4);
    unsigned r = (x + 0x7fffu + ((x >> 16) & 1u)) >> 16;  // round-nearest-even
    return (u16)r;
}
__device__ __forceinline__ float expc(float e) {
    return expf(fminf(e, 80.0f));
}

// ---------------------------------------------------------------------------
// MFMA projection GEMM.  grid = (64, M/128, 8), block = 256.
// ---------------------------------------------------------------------------
template<int MODE>
__global__ __launch_bounds__(256) void gemm_proj(
    const float* __restrict__ W, const float* __restrict__ bias,
    const float* __restrict__ x, const u16* __restrict__ XR,
    u16* __restrict__ outb, float* __restrict__ outf)
{
    const int tid  = threadIdx.x;
    const int b    = blockIdx.z;
    const int n0   = blockIdx.x * 128;
    const int m0   = blockIdx.y * 128;
    const int wv   = tid >> 6;
    const int lane = tid & 63;
    const int lr   = lane & 15;     // frag row (A/B read), frag col (D write)
    const int lg   = lane >> 4;     // frag k-granule, D row group
    const int wm   = (wv & 1) * 64;
    const int wn   = (wv >> 1) * 64;

    __shared__ __align__(16) short lA[128 * 64];  // [m][k] bf16, swizzled
    __shared__ __align__(16) short lB[128 * 64];  // [n][k] bf16, swizzled

    f32x4 acc[4][4];
    const f32x4 zero = {0.f, 0.f, 0.f, 0.f};
#pragma unroll
    for (int i = 0; i < 4; ++i)
#pragma unroll
        for (int j = 0; j < 4; ++j) acc[i][j] = zero;

    // staging slot mapping
    const int am   = tid >> 3;          // A row base (q adds 32)
    const int akg  = tid & 7;           // A k-granule (8 bf16)
    const int xn   = tid & 127;         // X column (n)
    const int xkgb = (tid >> 7) * 4;    // X k-granule base

    s16x8 aS[4], xS[4];

    auto loadstep = [&](int ks) {
        const int k0 = ks * 64;
#pragma unroll
        for (int q = 0; q < 4; ++q) {
            const int m = am + q * 32;
            const float* src = W + (size_t)(m0 + m) * 512 + k0 + akg * 8;
            f32x4 u0 = *(const f32x4*)src;
            f32x4 u1 = *(const f32x4*)(src + 4);
            s16x8 r;
#pragma unroll
            for (int j = 0; j < 4; ++j) {
                r[j]     = (short)f2b(u0[j]);
                r[4 + j] = (short)f2b(u1[j]);
            }
            aS[q] = r;
        }
#pragma unroll
        for (int q = 0; q < 4; ++q) {
            const int kg = xkgb + q;
            s16x8 r;
#pragma unroll
            for (int j = 0; j < 8; ++j) {
                const int k = k0 + kg * 8 + j;
                const size_t idx = ((size_t)(b * 512 + k)) * 8192 + n0 + xn;
                float v = x[idx];
                if (MODE == 2) v -= b2f(XR[idx]);
                r[j] = (short)f2b(v);
            }
            xS[q] = r;
        }
    };

    auto writestep = [&]() {
#pragma unroll
        for (int q = 0; q < 4; ++q) {
            const int m = am + q * 32;
            *(s16x8*)(lA + m * 64 + ((akg ^ (m & 7)) << 3)) = aS[q];
        }
#pragma unroll
        for (int q = 0; q < 4; ++q) {
            const int kg = xkgb + q;
            *(s16x8*)(lB + xn * 64 + ((kg ^ (xn & 7)) << 3)) = xS[q];
        }
    };

    loadstep(0);
    for (int ks = 0; ks < 8; ++ks) {
        __syncthreads();              // previous compute done reading LDS
        writestep();
        __syncthreads();              // tile visible
        if (ks < 7) loadstep(ks + 1); // overlap next loads with MFMA
#pragma unroll
        for (int kk = 0; kk < 2; ++kk) {
            const int g = kk * 4 + lg;
            s16x8 af[4], bf[4];
#pragma unroll
            for (int f = 0; f < 4; ++f) {
                const int r = wm + f * 16 + lr;
                af[f] = *(const s16x8*)(lA + r * 64 + ((g ^ (r & 7)) << 3));
            }
#pragma unroll
            for (int f = 0; f < 4; ++f) {
                const int r = wn + f * 16 + lr;
                bf[f] = *(const s16x8*)(lB + r * 64 + ((g ^ (r & 7)) << 3));
            }
#pragma unroll
            for (int fm = 0; fm < 4; ++fm)
#pragma unroll
                for (int fn = 0; fn < 4; ++fn)
                    acc[fm][fn] = __builtin_amdgcn_mfma_f32_16x16x32_bf16(
                        af[fm], bf[fn], acc[fm][fn], 0, 0, 0);
        }
    }

    // epilogue: D frag lane mapping col = lane&15, row = (lane>>4)*4 + r
#pragma unroll
    for (int fm = 0; fm < 4; ++fm) {
        const int m = m0 + wm + fm * 16 + lg * 4;
#pragma unroll
        for (int fn = 0; fn < 4; ++fn) {
            const int n = n0 + wn + fn * 16 + lr;
            if (MODE == 0) {
                const size_t base =
                    ((size_t)((b * 8 + (n & 7)) * 1024 + (n >> 3))) * 128 + m;
                u16x4 o;
#pragma unroll
                for (int r = 0; r < 4; ++r) o[r] = f2b(acc[fm][fn][r]);
                *(u16x4*)(outb + base) = o;
            } else if (MODE == 1) {
                const size_t base =
                    ((size_t)((b * 8 + (n & 7)) * 1024 + (n >> 3))) * 512 + m;
                u16x4 o;
#pragma unroll
                for (int r = 0; r < 4; ++r)
                    o[r] = f2b(acc[fm][fn][r] + bias[m + r]);
                *(u16x4*)(outb + base) = o;
            } else {
#pragma unroll
                for (int r = 0; r < 4; ++r)
                    outf[((size_t)(b * 512 + m + r)) * 8192 + n] =
                        acc[fm][fn][r] + bias[m + r];
            }
        }
    }
}

// ---------------------------------------------------------------------------
// K2: block = 4 waves; wave = (s, j). Lane-serial dot over d, LDS reduce.
// ---------------------------------------------------------------------------
__global__ __launch_bounds__(256) void k2_lsum(
    const u16* Qs, float* lbuf)
{
    const int tid  = threadIdx.x;
    const int wv   = tid >> 6;
    const int lane = tid & 63;
    const int gw   = blockIdx.x * 4 + wv;     // 0..65535
    const int s    = gw >> 10;
    const int j    = gw & 1023;
    const u16* q = Qs + (long)s * 1024 * 128;

    float sum = 0.f;
    for (int i = lane; i < 1024; i += 64) {
        float e = 0.f;
        for (int d = 0; d < 128; ++d)
            e += b2f(q[i * 128 + d]) * b2f(q[j * 128 + d]);
        sum += expc(e);
    }
    __shared__ float red[256];
    red[tid] = sum;
    __syncthreads();
    for (int o = 32; o > 0; o >>= 1) {
        if (lane < o) red[tid] += red[tid + o];
        __syncthreads();
    }
    if (lane == 0)
        lbuf[s * 1024 + j] = red[wv * 64] * (1.0f + 1e-9f);
}

// ---------------------------------------------------------------------------
// K4: block = (jt, s); j-tile 16, all 512 c, i in tiles of 64.
// ---------------------------------------------------------------------------
__global__ __launch_bounds__(256) void k4_xr(
    const u16* Qs, const u16* Vt, const float* lbuf, u16* XR)
{
    const int tid = threadIdx.x;
    const int jt  = blockIdx.x;        // 0..63
    const int s   = blockIdx.y;        // 0..63
    const int b   = s >> 3, w = s & 7;
    const int j0  = jt * 16;
    const u16* q = Qs + (long)s * 1024 * 128;
    const u16* v = Vt + (long)s * 1024 * 512;

    __shared__ u16   qj[16][128];
    __shared__ float att[64][17];
    __shared__ float rls[16];

    for (int idx = tid; idx < 16 * 128; idx += 256)
        qj[idx >> 7][idx & 127] = q[(j0 + (idx >> 7)) * 128 + (idx & 127)];
    if (tid < 16)
        rls[tid] = 1.0f / lbuf[s * 1024 + j0 + tid];

    const int ii = tid & 63;       // E-phase row
    const int jg = tid >> 6;       // E-phase j-group (4 j each)
    const int c0 = tid;            // MAC-phase channels
    const int c1 = tid + 256;

    float accA[16], accB[16];
    for (int j = 0; j < 16; ++j) { accA[j] = 0.f; accB[j] = 0.f; }

    for (int it = 0; it < 16; ++it) {
        const int i0 = it * 64;
        __syncthreads();   // staging done (it==0) / previous MAC reads done
        float e[4];
        e[0] = e[1] = e[2] = e[3] = 0.f;
        for (int d = 0; d < 128; ++d) {
            const float qv = b2f(q[(i0 + ii) * 128 + d]);
            for (int jj = 0; jj < 4; ++jj)
                e[jj] += qv * b2f(qj[jg * 4 + jj][d]);
        }
        for (int jj = 0; jj < 4; ++jj) {
            const int j = jg * 4 + jj;
            att[ii][j] = expc(e[jj]) * rls[j];
        }
        __syncthreads();
        for (int i2 = 0; i2 < 64; ++i2) {
            const float va = b2f(v[(i0 + i2) * 512 + c0]);
            const float vb = b2f(v[(i0 + i2) * 512 + c1]);
            for (int j = 0; j < 16; ++j) {
                const float a = att[i2][j];
                accA[j] += va * a;
                accB[j] += vb * a;
            }
        }
    }
    for (int j = 0; j < 16; ++j) {
        XR[((long)(b * 512 + c0)) * 8192 + (j0 + j) * 8 + w] = f2b(accA[j]);
        XR[((long)(b * 512 + c1)) * 8192 + (j0 + j) * 8 + w] = f2b(accB[j]);
    }
}

// ---------------------------------------------------------------------------
// K6: one block per channel; float4 loads; deterministic LDS reduction.
// ---------------------------------------------------------------------------
__global__ __launch_bounds__(256) void k6_bnstats(
    const float* T, const float* gamma, const float* beta, float* bnp)
{
    const int c   = blockIdx.x;
    const int tid = threadIdx.x;
    float s1 = 0.f, s2 = 0.f;
    for (int b = 0; b < 8; ++b) {
        const f32x4* p = (const f32x4*)(T + ((long)(b * 512 + c)) * 8192);
        for (int m = 0; m < 8; ++m) {
            const f32x4 f = p[m * 256 + tid];
#pragma unroll
            for (int j = 0; j < 4; ++j) { s1 += f[j]; s2 += f[j] * f[j]; }
        }
    }
    __shared__ float r1[256], r2[256];
    r1[tid] = s1; r2[tid] = s2;
    __syncthreads();
    for (int o = 128; o > 0; o >>= 1) {
        if (tid < o) { r1[tid] += r1[tid + o]; r2[tid] += r2[tid + o]; }
        __syncthreads();
    }
    if (tid == 0) {
        const float inv_n = 1.0f / 65536.0f;
        const float mean = r1[0] * inv_n;
        const float var  = r2[0] * inv_n - mean * mean;
        const float sc   = gamma[c] * rsqrtf(var + 1e-5f);
        bnp[c]       = sc;
        bnp[512 + c] = beta[c] - mean * sc;
    }
}

// ---------------------------------------------------------------------------
// K7: out = x + relu(T*scale + shift), in place, float4 vectorized.
// ---------------------------------------------------------------------------
__global__ __launch_bounds__(256) void k7_final(
    const float* x, const float* bnp, float* out)
{
    const long i = ((long)blockIdx.x * 256 + threadIdx.x) * 4;  // 2^25 elems
    const int c = (int)((i >> 13) & 511);   // 8192 % 4 == 0 -> same c for all 4
    const float sc = bnp[c], sh = bnp[512 + c];
    f32x4 t  = *(const f32x4*)(out + i);
    f32x4 xv = *(const f32x4*)(x + i);
    f32x4 r;
#pragma unroll
    for (int j = 0; j < 4; ++j) {
        float v = t[j] * sc + sh;
        if (v < 0.f) v = 0.f;
        r[j] = xv[j] + v;
    }
    *(f32x4*)(out + i) = r;
}

extern "C" void kernel_launch(void* const* d_in, const int* in_sizes, int n_in,
                              void* d_out, int out_size, void* d_ws, size_t ws_size,
                              hipStream_t stream)
{
    const float* x     = (const float*)d_in[0];
    const float* qk_w  = (const float*)d_in[1];
    const float* v_w   = (const float*)d_in[2];
    const float* v_b   = (const float*)d_in[3];
    const float* t_w   = (const float*)d_in[4];
    const float* t_b   = (const float*)d_in[5];
    const float* gamma = (const float*)d_in[6];
    const float* beta  = (const float*)d_in[7];
    float* out = (float*)d_out;

    char* ws = (char*)d_ws;
    u16*   Qs   = (u16*)(ws);                    // 16 MiB  [64][1024][128]
    u16*   Vt   = (u16*)(ws + 16777216);         // 64 MiB  [64][1024][512]
    u16*   XR   = (u16*)(ws + 83886080);         // 64 MiB  x-layout
    float* lbuf = (float*)(ws + 150994944);      // 256 KiB [64][1024]
    float* bnp  = (float*)(ws + 151257088);      // 4 KiB
    // total ws use: 151,261,184 B (~144.3 MiB) — unchanged from round 5

    gemm_proj<0><<<dim3(64, 1, 8), 256, 0, stream>>>(
        qk_w, nullptr, x, nullptr, Qs, nullptr);
    k2_lsum  <<<dim3(64 * 1024 / 4), 256, 0, stream>>>(Qs, lbuf);
    gemm_proj<1><<<dim3(64, 4, 8), 256, 0, stream>>>(
        v_w, v_b, x, nullptr, Vt, nullptr);
    k4_xr    <<<dim3(64, 64), 256, 0, stream>>>(Qs, Vt, lbuf, XR);
    gemm_proj<2><<<dim3(64, 4, 8), 256, 0, stream>>>(
        t_w, t_b, x, XR, nullptr, out);
    k6_bnstats <<<dim3(512), 256, 0, stream>>>(out, gamma, beta, bnp);
    k7_final <<<dim3(33554432 / 1024), 256, 0, stream>>>(x, bnp, out);
}

// Round 3
// 953.961 us; speedup vs baseline: 5.1004x; 5.1004x over previous
//
#include <hip/hip_runtime.h>
#include <math.h>

// SA_Layer2 — ROUND 8: fix round-7's tr-read addressing.
// ds_read_b64_tr_b16 semantics (m156+m162 jointly): lane byte-addr a reads
// column (a>>3)&15 of the 128B-aligned [4][16] bf16 subtile containing a,
// elems j=0..3 at rows j.  Correct per-lane addr = subtile_base + 8*lane
// (NOT 2*(l&15)+128*(l>>4), which collapsed 4 lanes onto one column -> the
// absmax=253 failure).  Also: LDS tiles must be 128B-aligned so HW subtile
// windows match ours.  Slot->i permutation identical on P(A) and V(B) sides
// => contraction exact.  All other logic unchanged from round 7.

typedef unsigned short u16;
typedef __attribute__((ext_vector_type(4))) float f32x4;
typedef __attribute__((ext_vector_type(8))) short s16x8;
typedef __attribute__((ext_vector_type(4))) short s16x4;
typedef __attribute__((ext_vector_type(4))) u16  u16x4;

__device__ __forceinline__ float b2f(u16 u) {
    unsigned x = ((unsigned)u) << 16;
    float f;
    __builtin_memcpy(&f, &x, 4);
    return f;
}
__device__ __forceinline__ u16 f2b(float f) {
    unsigned x;
    __builtin_memcpy(&x, &f, 4);
    unsigned r = (x + 0x7fffu + ((x >> 16) & 1u)) >> 16;  // round-nearest-even
    return (u16)r;
}
__device__ __forceinline__ float expc(float e) {
    return expf(fminf(e, 80.0f));
}

// ---------------------------------------------------------------------------
// MFMA projection GEMM.  grid = (64, M/128, 8), block = 256.   (round-6, green)
// ---------------------------------------------------------------------------
template<int MODE>
__global__ __launch_bounds__(256) void gemm_proj(
    const float* __restrict__ W, const float* __restrict__ bias,
    const float* __restrict__ x, const u16* __restrict__ XR,
    u16* __restrict__ outb, float* __restrict__ outf)
{
    const int tid  = threadIdx.x;
    const int b    = blockIdx.z;
    const int n0   = blockIdx.x * 128;
    const int m0   = blockIdx.y * 128;
    const int wv   = tid >> 6;
    const int lane = tid & 63;
    const int lr   = lane & 15;
    const int lg   = lane >> 4;
    const int wm   = (wv & 1) * 64;
    const int wn   = (wv >> 1) * 64;

    __shared__ __align__(16) short lA[128 * 64];
    __shared__ __align__(16) short lB[128 * 64];

    f32x4 acc[4][4];
    const f32x4 zero = {0.f, 0.f, 0.f, 0.f};
#pragma unroll
    for (int i = 0; i < 4; ++i)
#pragma unroll
        for (int j = 0; j < 4; ++j) acc[i][j] = zero;

    const int am   = tid >> 3;
    const int akg  = tid & 7;
    const int xn   = tid & 127;
    const int xkgb = (tid >> 7) * 4;

    s16x8 aS[4], xS[4];

    auto loadstep = [&](int ks) {
        const int k0 = ks * 64;
#pragma unroll
        for (int q = 0; q < 4; ++q) {
            const int m = am + q * 32;
            const float* src = W + (size_t)(m0 + m) * 512 + k0 + akg * 8;
            f32x4 u0 = *(const f32x4*)src;
            f32x4 u1 = *(const f32x4*)(src + 4);
            s16x8 r;
#pragma unroll
            for (int j = 0; j < 4; ++j) {
                r[j]     = (short)f2b(u0[j]);
                r[4 + j] = (short)f2b(u1[j]);
            }
            aS[q] = r;
        }
#pragma unroll
        for (int q = 0; q < 4; ++q) {
            const int kg = xkgb + q;
            s16x8 r;
#pragma unroll
            for (int j = 0; j < 8; ++j) {
                const int k = k0 + kg * 8 + j;
                const size_t idx = ((size_t)(b * 512 + k)) * 8192 + n0 + xn;
                float v = x[idx];
                if (MODE == 2) v -= b2f(XR[idx]);
                r[j] = (short)f2b(v);
            }
            xS[q] = r;
        }
    };

    auto writestep = [&]() {
#pragma unroll
        for (int q = 0; q < 4; ++q) {
            const int m = am + q * 32;
            *(s16x8*)(lA + m * 64 + ((akg ^ (m & 7)) << 3)) = aS[q];
        }
#pragma unroll
        for (int q = 0; q < 4; ++q) {
            const int kg = xkgb + q;
            *(s16x8*)(lB + xn * 64 + ((kg ^ (xn & 7)) << 3)) = xS[q];
        }
    };

    loadstep(0);
    for (int ks = 0; ks < 8; ++ks) {
        __syncthreads();
        writestep();
        __syncthreads();
        if (ks < 7) loadstep(ks + 1);
#pragma unroll
        for (int kk = 0; kk < 2; ++kk) {
            const int g = kk * 4 + lg;
            s16x8 af[4], bf[4];
#pragma unroll
            for (int f = 0; f < 4; ++f) {
                const int r = wm + f * 16 + lr;
                af[f] = *(const s16x8*)(lA + r * 64 + ((g ^ (r & 7)) << 3));
            }
#pragma unroll
            for (int f = 0; f < 4; ++f) {
                const int r = wn + f * 16 + lr;
                bf[f] = *(const s16x8*)(lB + r * 64 + ((g ^ (r & 7)) << 3));
            }
#pragma unroll
            for (int fm = 0; fm < 4; ++fm)
#pragma unroll
                for (int fn = 0; fn < 4; ++fn)
                    acc[fm][fn] = __builtin_amdgcn_mfma_f32_16x16x32_bf16(
                        af[fm], bf[fn], acc[fm][fn], 0, 0, 0);
        }
    }

#pragma unroll
    for (int fm = 0; fm < 4; ++fm) {
        const int m = m0 + wm + fm * 16 + lg * 4;
#pragma unroll
        for (int fn = 0; fn < 4; ++fn) {
            const int n = n0 + wn + fn * 16 + lr;
            if (MODE == 0) {
                const size_t base =
                    ((size_t)((b * 8 + (n & 7)) * 1024 + (n >> 3))) * 128 + m;
                u16x4 o;
#pragma unroll
                for (int r = 0; r < 4; ++r) o[r] = f2b(acc[fm][fn][r]);
                *(u16x4*)(outb + base) = o;
            } else if (MODE == 1) {
                const size_t base =
                    ((size_t)((b * 8 + (n & 7)) * 1024 + (n >> 3))) * 512 + m;
                u16x4 o;
#pragma unroll
                for (int r = 0; r < 4; ++r)
                    o[r] = f2b(acc[fm][fn][r] + bias[m + r]);
                *(u16x4*)(outb + base) = o;
            } else {
#pragma unroll
                for (int r = 0; r < 4; ++r)
                    outf[((size_t)(b * 512 + m + r)) * 8192 + n] =
                        acc[fm][fn][r] + bias[m + r];
            }
        }
    }
}

// ---------------------------------------------------------------------------
// k4_fused: attention (E, exp, colsum, PV, normalize) all-MFMA.
// grid = (32 j-tiles, 64 slices), block = 256 (4 waves).
// ---------------------------------------------------------------------------
__global__ __launch_bounds__(256) void k4_fused(
    const u16* __restrict__ Qs, const u16* __restrict__ Vt, u16* __restrict__ XR)
{
    const int tid  = threadIdx.x;
    const int jt   = blockIdx.x;       // 0..31
    const int s    = blockIdx.y;       // 0..63
    const int b    = s >> 3, wimg = s & 7;
    const int j0   = jt * 32;
    const int w    = tid >> 6;
    const int lane = tid & 63;
    const int l15  = lane & 15;
    const int lg   = lane >> 4;
    const int jsub = w & 1;
    const int ih   = w >> 1;           // E: i-sub;  PV: c-half

    __shared__ __align__(128) short Vl[32 * 512];   // [cg32][i/4 8][4][16]
    __shared__ __align__(128) short Pl[2 * 8 * 64]; // [jg2][i/4 8][4][16]
    __shared__ float csum_lds[2][32];
    __shared__ float rls_lds[32];

    const unsigned vbase = (unsigned)(uintptr_t)(void*)Vl;
    const unsigned pbase = (unsigned)(uintptr_t)(void*)Pl;
    const long qrow = (long)s * 1024;

    // preload Q_j B-frags (wave's 16 j rows, K=128)
    s16x8 qj[4];
    {
        const int j = j0 + jsub * 16 + l15;
#pragma unroll
        for (int kk = 0; kk < 4; ++kk)
            qj[kk] = *(const s16x8*)(Qs + (qrow + j) * 128 + (kk * 4 + lg) * 8);
    }

    f32x4 acc[16];
    const f32x4 zero = {0.f, 0.f, 0.f, 0.f};
#pragma unroll
    for (int f = 0; f < 16; ++f) acc[f] = zero;
    float csum = 0.f;

    // tr-read lane offset: addr = subtile_stack_base + 8*lane
    //   -> column (l&15) of subtile (l>>4) within the 4-subtile stack.
    const unsigned lanebyte = (unsigned)(lane * 8);

    for (int it = 0; it < 32; ++it) {
        const int i0 = it * 32;
        __syncthreads();   // prev PV done reading Vl & Pl

        // ---- stage V[i0..i0+32][0..512] -> Vl subtiled (b128 writes) ----
        {
            const int cg8 = tid & 63;
            const int ib  = tid >> 6;          // 0..3
            const int c0  = cg8 * 8;
            const int sub = (c0 >> 4) * 8;     // cgroup*8
            const int off = c0 & 15;
#pragma unroll
            for (int q = 0; q < 8; ++q) {
                const int i = ib + q * 4;
                s16x8 v = *(const s16x8*)(Vt + (qrow + i0 + i) * 512 + c0);
                *(s16x8*)(Vl + (sub + (i >> 2)) * 64 + (i & 3) * 16 + off) = v;
            }
        }
        // ---- E phase: 16x16 tile, exp, colsum, P write ----
        {
            const int irow = i0 + ih * 16 + l15;
            f32x4 e = zero;
#pragma unroll
            for (int kk = 0; kk < 4; ++kk) {
                s16x8 qa = *(const s16x8*)(Qs + (qrow + irow) * 128 + (kk * 4 + lg) * 8);
                e = __builtin_amdgcn_mfma_f32_16x16x32_bf16(qa, qj[kk], e, 0, 0, 0);
            }
#pragma unroll
            for (int r = 0; r < 4; ++r) {
                const float pe = expc(e[r]);
                csum += pe;
                const int il = ih * 16 + 4 * lg + r;         // local i (0..31)
                Pl[(jsub * 8 + (il >> 2)) * 64 + (il & 3) * 16 + l15] =
                    (short)f2b(pe);
            }
        }
        __syncthreads();   // Vl + Pl visible

        // ---- PV phase: tr-reads + MFMAs, 4-frag batches, counted waits ----
        {
            const unsigned abase = pbase + (unsigned)(jsub * 1024) + lanebyte;
            s16x4 pa0, pa1;
            asm volatile("ds_read_b64_tr_b16 %0, %1" : "=v"(pa0) : "v"(abase));
            asm volatile("ds_read_b64_tr_b16 %0, %1" : "=v"(pa1) : "v"(abase + 512u));
            const unsigned bstart = vbase + (unsigned)(ih * 16384) + lanebyte;
            s16x4 bb[2][4][2];
#pragma unroll
            for (int f = 0; f < 4; ++f) {
                const unsigned ba = bstart + (unsigned)(f * 1024);
                asm volatile("ds_read_b64_tr_b16 %0, %1" : "=v"(bb[0][f][0]) : "v"(ba));
                asm volatile("ds_read_b64_tr_b16 %0, %1" : "=v"(bb[0][f][1]) : "v"(ba + 512u));
            }
            s16x8 af;
#pragma unroll
            for (int bt = 0; bt < 4; ++bt) {
                if (bt < 3) {
#pragma unroll
                    for (int f = 0; f < 4; ++f) {
                        const unsigned ba =
                            bstart + (unsigned)(((bt + 1) * 4 + f) * 1024);
                        asm volatile("ds_read_b64_tr_b16 %0, %1"
                                     : "=v"(bb[(bt + 1) & 1][f][0]) : "v"(ba));
                        asm volatile("ds_read_b64_tr_b16 %0, %1"
                                     : "=v"(bb[(bt + 1) & 1][f][1]) : "v"(ba + 512u));
                    }
                    asm volatile("s_waitcnt lgkmcnt(8)");
                } else {
                    asm volatile("s_waitcnt lgkmcnt(0)");
                }
                __builtin_amdgcn_sched_barrier(0);
                if (bt == 0) {
#pragma unroll
                    for (int j = 0; j < 4; ++j) { af[j] = pa0[j]; af[4 + j] = pa1[j]; }
                }
#pragma unroll
                for (int f = 0; f < 4; ++f) {
                    s16x8 bf;
#pragma unroll
                    for (int j = 0; j < 4; ++j) {
                        bf[j]     = bb[bt & 1][f][0][j];
                        bf[4 + j] = bb[bt & 1][f][1][j];
                    }
                    acc[bt * 4 + f] = __builtin_amdgcn_mfma_f32_16x16x32_bf16(
                        af, bf, acc[bt * 4 + f], 0, 0, 0);
                }
            }
        }
    }

    // ---- colsum reduce -> rls ----
    __syncthreads();
    csum += __shfl_xor(csum, 16, 64);
    csum += __shfl_xor(csum, 32, 64);
    if (lane < 16) csum_lds[ih][jsub * 16 + lane] = csum;
    __syncthreads();
    if (tid < 32)
        rls_lds[tid] = 1.0f / ((1.0f + 1e-9f) * (csum_lds[0][tid] + csum_lds[1][tid]));
    __syncthreads();

    // ---- epilogue: scale by rls[j], store XR (x-layout) ----
#pragma unroll
    for (int f = 0; f < 16; ++f) {
        const int c = ih * 256 + f * 16 + l15;
        u16* dst = XR + ((size_t)(b * 512 + c)) * 8192;
#pragma unroll
        for (int r = 0; r < 4; ++r) {
            const int jl = jsub * 16 + 4 * lg + r;
            dst[(j0 + jl) * 8 + wimg] = f2b(acc[f][r] * rls_lds[jl]);
        }
    }
}

// ---------------------------------------------------------------------------
// K6: one block per channel; float4 loads; deterministic LDS reduction.
// ---------------------------------------------------------------------------
__global__ __launch_bounds__(256) void k6_bnstats(
    const float* T, const float* gamma, const float* beta, float* bnp)
{
    const int c   = blockIdx.x;
    const int tid = threadIdx.x;
    float s1 = 0.f, s2 = 0.f;
    for (int b = 0; b < 8; ++b) {
        const f32x4* p = (const f32x4*)(T + ((long)(b * 512 + c)) * 8192);
        for (int m = 0; m < 8; ++m) {
            const f32x4 f = p[m * 256 + tid];
#pragma unroll
            for (int j = 0; j < 4; ++j) { s1 += f[j]; s2 += f[j] * f[j]; }
        }
    }
    __shared__ float r1[256], r2[256];
    r1[tid] = s1; r2[tid] = s2;
    __syncthreads();
    for (int o = 128; o > 0; o >>= 1) {
        if (tid < o) { r1[tid] += r1[tid + o]; r2[tid] += r2[tid + o]; }
        __syncthreads();
    }
    if (tid == 0) {
        const float inv_n = 1.0f / 65536.0f;
        const float mean = r1[0] * inv_n;
        const float var  = r2[0] * inv_n - mean * mean;
        const float sc   = gamma[c] * rsqrtf(var + 1e-5f);
        bnp[c]       = sc;
        bnp[512 + c] = beta[c] - mean * sc;
    }
}

// ---------------------------------------------------------------------------
// K7: out = x + relu(T*scale + shift), in place, float4 vectorized.
// ---------------------------------------------------------------------------
__global__ __launch_bounds__(256) void k7_final(
    const float* x, const float* bnp, float* out)
{
    const long i = ((long)blockIdx.x * 256 + threadIdx.x) * 4;
    const int c = (int)((i >> 13) & 511);
    const float sc = bnp[c], sh = bnp[512 + c];
    f32x4 t  = *(const f32x4*)(out + i);
    f32x4 xv = *(const f32x4*)(x + i);
    f32x4 r;
#pragma unroll
    for (int j = 0; j < 4; ++j) {
        float v = t[j] * sc + sh;
        if (v < 0.f) v = 0.f;
        r[j] = xv[j] + v;
    }
    *(f32x4*)(out + i) = r;
}

extern "C" void kernel_launch(void* const* d_in, const int* in_sizes, int n_in,
                              void* d_out, int out_size, void* d_ws, size_t ws_size,
                              hipStream_t stream)
{
    const float* x     = (const float*)d_in[0];
    const float* qk_w  = (const float*)d_in[1];
    const float* v_w   = (const float*)d_in[2];
    const float* v_b   = (const float*)d_in[3];
    const float* t_w   = (const float*)d_in[4];
    const float* t_b   = (const float*)d_in[5];
    const float* gamma = (const float*)d_in[6];
    const float* beta  = (const float*)d_in[7];
    float* out = (float*)d_out;

    char* ws = (char*)d_ws;
    u16*   Qs   = (u16*)(ws);                    // 16 MiB  [64][1024][128]
    u16*   Vt   = (u16*)(ws + 16777216);         // 64 MiB  [64][1024][512]
    u16*   XR   = (u16*)(ws + 83886080);         // 64 MiB  x-layout
    float* bnp  = (float*)(ws + 151257088);      // 4 KiB
    // ws layout unchanged (lbuf slot unused)

    gemm_proj<0><<<dim3(64, 1, 8), 256, 0, stream>>>(
        qk_w, nullptr, x, nullptr, Qs, nullptr);
    gemm_proj<1><<<dim3(64, 4, 8), 256, 0, stream>>>(
        v_w, v_b, x, nullptr, Vt, nullptr);
    k4_fused <<<dim3(32, 64), 256, 0, stream>>>(Qs, Vt, XR);
    gemm_proj<2><<<dim3(64, 4, 8), 256, 0, stream>>>(
        t_w, t_b, x, XR, nullptr, out);
    k6_bnstats <<<dim3(512), 256, 0, stream>>>(out, gamma, beta, bnp);
    k7_final <<<dim3(33554432 / 1024), 256, 0, stream>>>(x, bnp, out);
}